// Round 1
// baseline (377.963 us; speedup 1.0000x reference)
//
#include <hip/hip_runtime.h>
#include <stdint.h>

typedef unsigned short u16;
typedef short short8 __attribute__((ext_vector_type(8)));
typedef float floatx4 __attribute__((ext_vector_type(4)));

#define NPERB   40000
#define NPTS    80000
#define KNBR    16
#define CIN     64
#define MDIM    16
#define CADD    3
#define CF      (CIN + CADD)
#define COUT    128
#define KF      1072
#define KP      1088
#define NKT     34        // KP/32 K-steps
#define PTSB    16        // points per block (2 per wave)
#define SLAB    65        // chunks per kt slab: 16 rows x 4 quads + 1 pad (odd)

__device__ __forceinline__ u16 f2bf(float f) {
    union { float f; unsigned int u; } v; v.f = f;
    unsigned int u = v.u;
    return (u16)((u + 0x7FFFu + ((u >> 16) & 1u)) >> 16);
}
__device__ __forceinline__ short8 pack8(floatx4 x, floatx4 y) {
    union { short8 v; u16 a[8]; } u;
    u.a[0] = f2bf(x[0]); u.a[1] = f2bf(x[1]); u.a[2] = f2bf(x[2]); u.a[3] = f2bf(x[3]);
    u.a[4] = f2bf(y[0]); u.a[5] = f2bf(y[1]); u.a[6] = f2bf(y[2]); u.a[7] = f2bf(y[3]);
    return u.v;
}
// 16B-chunk XOR swizzle: spreads bank columns; injective per 8-chunk group.
__device__ __forceinline__ unsigned swz(unsigned chunk) {
    return chunk ^ ((chunk >> 3) & 7u);
}
// async global -> LDS, 16B per lane; LDS dest = uniform base + lane*16 (linear).
__device__ __forceinline__ void gload_lds16(const void* g, void* l) {
    __builtin_amdgcn_global_load_lds(
        (const __attribute__((address_space(1))) void*)g,
        (__attribute__((address_space(3))) void*)l, 16, 0, 0);
}

// Convert+pad linear_weight fp32 [128,1072] -> bf16 ws [128,1088] (zero pad).
__global__ void prep_lw_kernel(const float* __restrict__ lw, u16* __restrict__ lwp) {
    int i = blockIdx.x * 256 + threadIdx.x;
    if (i >= COUT * KP) return;
    int o = i / KP, f = i - o * KP;
    lwp[i] = (f < KF) ? f2bf(lw[(size_t)o * KF + f]) : (u16)0;
}

// One point of phase 1: pconv row -> Apc (MFMA-A chunk layout, swizzled).
// wl = this point's wn (256 floats) staged in LDS; reads are wave-uniform
// ds_read_b128 broadcasts (no bank conflicts, no SGPR pressure).
__device__ __forceinline__ void compute_point(
    int pr, int lane, float av, const float (&fv)[KNBR],
    const float* wl, u16* Apc)
{
    const int em = lane & 15, ec = lane >> 4;
    // extra channels 64..66 (67 = zero pad): lane -> f = 1024 + lane
    float ev = 0.f;
#pragma unroll
    for (int k = 0; k < KNBR; k++)
        ev += __shfl(av, k * CADD + ec) * wl[k * MDIM + em];
    if (ec == 3) ev = 0.f;
    {
        unsigned kt   = 32 + (lane >> 5);
        unsigned quad = (lane >> 3) & 3;
        unsigned ch   = kt * SLAB + (unsigned)pr * 4 + quad;
        Apc[swz(ch) * 8 + (lane & 7)] = f2bf(ev);
    }
    // main channels: lane = c (0..63)
    floatx4 a0 = 0, a1 = 0, a2 = 0, a3 = 0;
#pragma unroll
    for (int k = 0; k < KNBR; k++) {
        const floatx4* w4 = (const floatx4*)(wl + k * MDIM);  // uniform -> broadcast
        const float fvk = fv[k];
        a0 += fvk * w4[0]; a1 += fvk * w4[1];
        a2 += fvk * w4[2]; a3 += fvk * w4[3];
    }
    {
        unsigned kt = lane >> 1, qb = (lane & 1) * 2;
        unsigned ch = kt * SLAB + (unsigned)pr * 4 + qb;
        *(short8*)&Apc[swz(ch) * 8]     = pack8(a0, a1);   // m 0..7
        *(short8*)&Apc[swz(ch + 1) * 8] = pack8(a2, a3);   // m 8..15
    }
}

// Fused: phase 1 builds pconv for 16 points directly in LDS; phase 2 does
// [16 x 1088] x [1088 x 128] with bf16 MFMA. Latency plan: per wave, ALL
// loads (2x wn->LDS async, addl, nbr s_loads -> 32 gathers) are issued
// before one vmcnt(0) wait -> ~2 exposed round-trips instead of ~12.
// LDS = 35.5K (Apc) + 16K (wn slots) = 51.9K -> 3 blocks/CU (24 waves).
__global__ __launch_bounds__(512, 6) void fused_kernel(
    const float* __restrict__ inp,   // [2,40000,64] fp32
    const int*   __restrict__ nbr,   // [2,40000,16] int32
    const float* __restrict__ wn,    // [2,40000,16,16] fp32
    const float* __restrict__ addl,  // [2,40000,16,3] fp32
    const u16*   __restrict__ lwp,   // [128,1088] bf16 (padded)
    const float* __restrict__ bias,  // [128] fp32
    float* __restrict__ out)         // [80000,128] fp32
{
    __shared__ __align__(16) u16   Apc[(NKT * SLAB + 8) * 8];   // 35488 B
    __shared__ __align__(16) float Wns[PTSB * KNBR * MDIM];     // 16384 B

    const int wave = threadIdx.x >> 6;
    const int lane = threadIdx.x & 63;
    const int pbase = blockIdx.x * PTSB;        // batch boundary 40000 % 16 == 0
    const float* inpb = inp + ((pbase >= NPERB) ? (size_t)NPERB * CIN : 0);

    // ---------------- phase 1: pconv -> LDS ----------------
    const int pr0 = wave * 2;                   // 2 points per wave
    const int p0  = __builtin_amdgcn_readfirstlane(pbase + pr0);
    const int p1  = p0 + 1;

    float* wl0 = Wns + pr0 * (KNBR * MDIM);
    float* wl1 = wl0 + KNBR * MDIM;
    // async wn staging: 1KB/point, one instruction each, zero VGPR cost
    gload_lds16(wn + (size_t)p0 * (KNBR * MDIM) + lane * 4, wl0);
    gload_lds16(wn + (size_t)p1 * (KNBR * MDIM) + lane * 4, wl1);

    // additional_features (48 floats/point) live in lanes 0..47
    float av0 = (lane < KNBR * CADD) ? addl[(size_t)p0 * (KNBR * CADD) + lane] : 0.f;
    float av1 = (lane < KNBR * CADD) ? addl[(size_t)p1 * (KNBR * CADD) + lane] : 0.f;

    // neighbor indices: uniform pointers -> s_loads (both points up front)
    const int* nb0 = nbr + (size_t)p0 * KNBR;
    const int* nb1 = nbr + (size_t)p1 * KNBR;
    int idx0[KNBR], idx1[KNBR];
#pragma unroll
    for (int k = 0; k < KNBR; k++) idx0[k] = nb0[k];
#pragma unroll
    for (int k = 0; k < KNBR; k++) idx1[k] = nb1[k];

    // all 32 gathers in flight (coalesced 256B/wave each)
    float fv0[KNBR], fv1[KNBR];
#pragma unroll
    for (int k = 0; k < KNBR; k++) fv0[k] = inpb[(size_t)idx0[k] * CIN + lane];
#pragma unroll
    for (int k = 0; k < KNBR; k++) fv1[k] = inpb[(size_t)idx1[k] * CIN + lane];

    // one wait covers wn->LDS staging + gathers + addl
    asm volatile("s_waitcnt vmcnt(0)" ::: "memory");
    __builtin_amdgcn_sched_barrier(0);

    compute_point(pr0,     lane, av0, fv0, wl0, Apc);
    compute_point(pr0 + 1, lane, av1, fv1, wl1, Apc);

    // ---------------- phase 2: GEMM [16 x KP] x [KP x 128] ----------------
    // wave tile: 16 points x 16 cols (c0 = wave*16).
    // mfma_f32_16x16x32_bf16: A[i=lane&15][k=quad*8+j], B[k][n=lane&15],
    // D[row=quad*4+r][col=lane&15]  (m89/m91-verified).
    const int r16 = lane & 15, quad = lane >> 4;
    const int c0 = wave * 16;
    const u16* Bp = lwp + (size_t)(c0 + r16) * KP + quad * 8;
    const unsigned abase = (unsigned)r16 * 4 + quad;
    const float bv = bias[c0 + r16];            // hoisted above the barrier

    __syncthreads();

    floatx4 acc = 0;
#pragma unroll 2
    for (int kt = 0; kt < NKT; kt++) {
        short8 A = *(const short8*)&Apc[swz((unsigned)kt * SLAB + abase) * 8];
        short8 B = *(const short8*)(Bp + kt * 32);
        acc = __builtin_amdgcn_mfma_f32_16x16x32_bf16(A, B, acc, 0, 0, 0);
    }

#pragma unroll
    for (int r = 0; r < 4; r++) {
        const size_t row = (size_t)(pbase + quad * 4 + r) * COUT;
        out[row + c0 + r16] = acc[r] + bv;
    }
}

// Fallback if ws can't hold the 278 KB padded LW (shouldn't happen): all-fp32,
// one block per point. Slow but correct.
__global__ __launch_bounds__(256) void fused_fallback_kernel(
    const float* __restrict__ inp, const int* __restrict__ nbr,
    const float* __restrict__ wn, const float* __restrict__ addl,
    const float* __restrict__ lw, const float* __restrict__ bias,
    float* __restrict__ out)
{
    const int p = blockIdx.x;
    const int b = p / NPERB;
    const int tid = threadIdx.x;
    __shared__ float sf[KNBR * CF];
    __shared__ float sw[KNBR * MDIM];
    __shared__ float sp[KF];

    sw[tid] = wn[(size_t)p * (KNBR * MDIM) + tid];
    for (int i = tid; i < KNBR * CIN; i += 256) {
        int k = i >> 6, c = i & 63;
        int idx = nbr[(size_t)p * KNBR + k];
        sf[k * CF + c] = inp[((size_t)b * NPERB + idx) * CIN + c];
    }
    if (tid < KNBR * CADD) {
        int k = tid / CADD, c = tid - k * CADD;
        sf[k * CF + CIN + c] = addl[(size_t)p * (KNBR * CADD) + tid];
    }
    __syncthreads();
    for (int f = tid; f < KF; f += 256) {
        int c = f >> 4, m = f & 15;
        float s = 0;
#pragma unroll
        for (int k = 0; k < KNBR; k++) s += sf[k * CF + c] * sw[k * MDIM + m];
        sp[f] = s;
    }
    __syncthreads();
    const int o = tid >> 1, h = tid & 1;
    float s = 0;
    for (int f = h * (KF / 2); f < (h + 1) * (KF / 2); f++)
        s += sp[f] * lw[(size_t)o * KF + f];
    s += __shfl_xor(s, 1);
    if (h == 0) out[(size_t)p * COUT + o] = s + bias[o];
}

extern "C" void kernel_launch(void* const* d_in, const int* in_sizes, int n_in,
                              void* d_out, int out_size, void* d_ws, size_t ws_size,
                              hipStream_t stream) {
    const float* inp  = (const float*)d_in[0];
    const int*   nbr  = (const int*)d_in[1];
    // d_in[2..4] = inverse_* (backward-only, unused)
    const float* wn   = (const float*)d_in[5];
    const float* addl = (const float*)d_in[6];
    const float* lw   = (const float*)d_in[7];
    const float* bias = (const float*)d_in[8];
    float* out = (float*)d_out;

    const size_t lw_bytes = (size_t)COUT * KP * sizeof(u16);  // 278528
    if (ws_size < lw_bytes) {
        fused_fallback_kernel<<<NPTS, 256, 0, stream>>>(inp, nbr, wn, addl, lw, bias, out);
        return;
    }
    u16* lwp = (u16*)d_ws;
    prep_lw_kernel<<<(COUT * KP + 255) / 256, 256, 0, stream>>>(lw, lwp);
    fused_kernel<<<NPTS / PTSB, 512, 0, stream>>>(inp, nbr, wn, addl, lwp, bias, out);
}